// Round 1
// baseline (640.856 us; speedup 1.0000x reference)
//
#include <hip/hip_runtime.h>
#include <hip/hip_fp16.h>

typedef _Float16 f16x8 __attribute__((ext_vector_type(8)));
typedef float    f32x4 __attribute__((ext_vector_type(4)));

#define T_STEPS 32
#define NROWS   10000
#define DDIM    256

// ---------------------------------------------------------------------------
// Pre-kernel: convert f32 weights to f16 in MFMA B-operand fragment order.
// dst[tid*8 + j] = W[cb*64 + et*16 + (lane&15)][ks*32 + (lane>>4)*8 + j]
// where tid = ((cb*4+et)*8+ks)*64 + lane. Main kernel then reads each
// fragment as one fully-coalesced 1 KiB wave load.
// ---------------------------------------------------------------------------
__global__ __launch_bounds__(256) void cvt_weights_kernel(
    const float* __restrict__ Aw, const float* __restrict__ Bw,
    _Float16* __restrict__ wsA, _Float16* __restrict__ wsB)
{
    int tid  = blockIdx.x * 256 + threadIdx.x;      // 0..8191
    int lane = tid & 63;
    int ks   = (tid >> 6) & 7;
    int et   = (tid >> 9) & 3;
    int cb   = tid >> 11;                           // 0..3
    int e     = cb * 64 + et * 16 + (lane & 15);
    int dbase = ks * 32 + (lane >> 4) * 8;
    size_t src = (size_t)e * DDIM + dbase;
    size_t dst = (size_t)tid * 8;
#pragma unroll
    for (int j = 0; j < 8; ++j) {
        wsA[dst + j] = (_Float16)Aw[src + j];
        wsB[dst + j] = (_Float16)Bw[src + j];
    }
}

// ---------------------------------------------------------------------------
// Fused SSM kernel. One block owns 32 rows for ALL 32 time steps (the
// recurrence is row-independent -> no inter-block communication).
// 4 waves; wave w computes output cols [64w, 64w+64). Per step:
//   acc = bias; acc += H_t @ Wb^T (f16 MFMA); acc += S_{t-1} @ Wa^T;
//   write S_t to LDS exchange (f16, XOR-swizzled) + to d_out (f32).
// ---------------------------------------------------------------------------
__global__ __launch_bounds__(256) void ssm_fused_kernel(
    const float* __restrict__ H,          // [T][N][D] f32
    const _Float16* __restrict__ WaF,     // frag-permuted f16
    const _Float16* __restrict__ WbF,
    const float* __restrict__ bias,       // [D] f32
    float* __restrict__ out)              // [T][N][D] f32
{
    __shared__ _Float16 Sx[32 * DDIM];    // 16 KiB S-exchange

    const int lane = threadIdx.x & 63;
    const int wave = threadIdx.x >> 6;    // 0..3
    const int lr   = lane & 15;
    const int kg   = lane >> 4;           // 0..3 (k-chunk of 8)
    const int row0 = blockIdx.x * 32;

    // clamped global H rows for the 2 row-tiles (tail block safety)
    int hrow[2];
#pragma unroll
    for (int nt = 0; nt < 2; ++nt) {
        int r = row0 + nt * 16 + lr;
        hrow[nt] = (r < NROWS) ? r : (NROWS - 1);
    }

    float bv[4];
#pragma unroll
    for (int et = 0; et < 4; ++et) bv[et] = bias[wave * 64 + et * 16 + lr];

    f32x4 acc[2][4];

    for (int t = 0; t < T_STEPS; ++t) {
        // init accumulators with bias (C/D layout: col = lane&15 -> bias only)
#pragma unroll
        for (int nt = 0; nt < 2; ++nt)
#pragma unroll
            for (int et = 0; et < 4; ++et)
#pragma unroll
                for (int i = 0; i < 4; ++i) acc[nt][et][i] = bv[et];

        // ---- B-GEMM: acc += H_t @ Wb^T ----
        const float* Ht = H + (size_t)t * NROWS * DDIM;
#pragma unroll
        for (int ks = 0; ks < 8; ++ks) {
            f16x8 ha[2];
#pragma unroll
            for (int nt = 0; nt < 2; ++nt) {
                const float* p = Ht + (size_t)hrow[nt] * DDIM + ks * 32 + kg * 8;
                f32x4 lo = *reinterpret_cast<const f32x4*>(p);
                f32x4 hi = *reinterpret_cast<const f32x4*>(p + 4);
                f16x8 a;
#pragma unroll
                for (int j = 0; j < 4; ++j) { a[j] = (_Float16)lo[j]; a[j + 4] = (_Float16)hi[j]; }
                ha[nt] = a;
            }
#pragma unroll
            for (int et = 0; et < 4; ++et) {
                f16x8 b = *reinterpret_cast<const f16x8*>(
                    WbF + (size_t)(((wave * 4 + et) * 8 + ks) * 64 + lane) * 8);
#pragma unroll
                for (int nt = 0; nt < 2; ++nt)
                    acc[nt][et] = __builtin_amdgcn_mfma_f32_16x16x32_f16(ha[nt], b, acc[nt][et], 0, 0, 0);
            }
        }

        // ---- A-GEMM: acc += S_{t-1} @ Wa^T (skip at t=0, S_0 = 0) ----
        if (t > 0) {
#pragma unroll
            for (int ks = 0; ks < 8; ++ks) {
                f16x8 sa[2];
#pragma unroll
                for (int nt = 0; nt < 2; ++nt) {
                    int r = nt * 16 + lr;
                    int byte_off = r * 512 + (((ks * 32 + kg * 8) * 2) ^ ((r & 7) << 4));
                    sa[nt] = *reinterpret_cast<const f16x8*>(
                        reinterpret_cast<const char*>(Sx) + byte_off);
                }
#pragma unroll
                for (int et = 0; et < 4; ++et) {
                    f16x8 b = *reinterpret_cast<const f16x8*>(
                        WaF + (size_t)(((wave * 4 + et) * 8 + ks) * 64 + lane) * 8);
#pragma unroll
                    for (int nt = 0; nt < 2; ++nt)
                        acc[nt][et] = __builtin_amdgcn_mfma_f32_16x16x32_f16(sa[nt], b, acc[nt][et], 0, 0, 0);
                }
            }
        }

        __syncthreads();   // all waves done READING old Sx

        // epilogue: S_t -> LDS exchange (f16) + d_out (f32)
        float* Ot = out + (size_t)t * NROWS * DDIM;
#pragma unroll
        for (int nt = 0; nt < 2; ++nt) {
#pragma unroll
            for (int et = 0; et < 4; ++et) {
#pragma unroll
                for (int i = 0; i < 4; ++i) {
                    int r = nt * 16 + kg * 4 + i;        // block row 0..31
                    int c = wave * 64 + et * 16 + lr;    // col 0..255
                    float v = acc[nt][et][i];
                    int so = r * 512 + ((c * 2) ^ ((r & 7) << 4));
                    *reinterpret_cast<_Float16*>(reinterpret_cast<char*>(Sx) + so) = (_Float16)v;
                    int gr = row0 + r;
                    if (gr < NROWS) Ot[(size_t)gr * DDIM + c] = v;
                }
            }
        }

        __syncthreads();   // new Sx visible to all waves
    }
}

extern "C" void kernel_launch(void* const* d_in, const int* in_sizes, int n_in,
                              void* d_out, int out_size, void* d_ws, size_t ws_size,
                              hipStream_t stream)
{
    const float* H  = (const float*)d_in[0];
    const float* Aw = (const float*)d_in[1];
    const float* Bw = (const float*)d_in[2];
    const float* Bb = (const float*)d_in[3];
    float* out      = (float*)d_out;

    _Float16* wsA = (_Float16*)d_ws;         // 128 KiB
    _Float16* wsB = wsA + 65536;             // 128 KiB

    cvt_weights_kernel<<<32, 256, 0, stream>>>(Aw, Bw, wsA, wsB);

    int nblocks = (NROWS + 31) / 32;         // 313
    ssm_fused_kernel<<<nblocks, 256, 0, stream>>>(H, wsA, wsB, Bb, out);
}

// Round 2
// 638.787 us; speedup vs baseline: 1.0032x; 1.0032x over previous
//
#include <hip/hip_runtime.h>
#include <hip/hip_fp16.h>

typedef _Float16 f16x8 __attribute__((ext_vector_type(8)));
typedef _Float16 f16x4 __attribute__((ext_vector_type(4)));
typedef float    f32x4 __attribute__((ext_vector_type(4)));

#define T_STEPS 32
#define NROWS   10000
#define DDIM    256
#define ROWS_PB 32

// ---------------------------------------------------------------------------
// Pre-kernel: convert f32 weights to f16 in MFMA B-operand fragment order.
// Fragment (ct, ks), ct=0..15 (16-col tile), ks=0..7 (K-chunk of 32):
//   dst[((ct*8+ks)*64 + lane)*8 + j] = W[ct*16 + (lane&15)][ks*32 + (lane>>4)*8 + j]
// Main kernel reads each fragment as one fully-coalesced 1 KiB wave load.
// ---------------------------------------------------------------------------
__global__ __launch_bounds__(256) void cvt_weights_kernel(
    const float* __restrict__ Aw, const float* __restrict__ Bw,
    _Float16* __restrict__ wsA, _Float16* __restrict__ wsB)
{
    int tid  = blockIdx.x * 256 + threadIdx.x;      // 0..8191
    int lane = tid & 63;
    int ks   = (tid >> 6) & 7;
    int ct   = tid >> 9;                            // 0..15
    int e     = ct * 16 + (lane & 15);
    int dbase = ks * 32 + (lane >> 4) * 8;
    size_t src = (size_t)e * DDIM + dbase;
    size_t dst = (size_t)tid * 8;
#pragma unroll
    for (int j = 0; j < 8; ++j) {
        wsA[dst + j] = (_Float16)Aw[src + j];
        wsB[dst + j] = (_Float16)Bw[src + j];
    }
}

// ---------------------------------------------------------------------------
// Fused SSM kernel. Block = 32 rows for all 32 steps (row-independent
// recurrence). 8 waves; wave w computes cols [32w, 32w+32).
// Double-buffered LDS: H tile (f16, staged via reg prefetch of H_{t+1}) and
// S-exchange (f16). ONE barrier per step. All tiles XOR-swizzled (r&7)<<4.
// ---------------------------------------------------------------------------
__global__ __launch_bounds__(512, 4) void ssm_fused_kernel(
    const float* __restrict__ H,          // [T][N][D] f32
    const _Float16* __restrict__ WaF,     // frag-permuted f16
    const _Float16* __restrict__ WbF,
    const float* __restrict__ bias,       // [D] f32
    float* __restrict__ out)              // [T][N][D] f32
{
    // [0,16K) Hbuf0 | [16K,32K) Hbuf1 | [32K,48K) Sx0 | [48K,64K) Sx1
    __shared__ char lds[65536];

    const int lane = threadIdx.x & 63;
    const int wave = threadIdx.x >> 6;    // 0..7
    const int lr   = lane & 15;
    const int kg   = lane >> 4;           // 0..3
    const int row0 = blockIdx.x * ROWS_PB;

    // rows this wave stages into LDS (4 rows/wave, clamped for tail block)
    int srow[4];
#pragma unroll
    for (int j = 0; j < 4; ++j) {
        int r = row0 + wave * 4 + j;
        srow[j] = (r < NROWS) ? r : (NROWS - 1);
    }

    float bv[2];
#pragma unroll
    for (int et = 0; et < 2; ++et) bv[et] = bias[wave * 32 + et * 16 + lr];

    // ---- prologue: stage H_0 into Hbuf0 ----
    f32x4 hreg[4];
#pragma unroll
    for (int j = 0; j < 4; ++j)
        hreg[j] = *reinterpret_cast<const f32x4*>(H + (size_t)srow[j] * DDIM + lane * 4);
#pragma unroll
    for (int j = 0; j < 4; ++j) {
        int r = wave * 4 + j;
        f16x4 v;
#pragma unroll
        for (int k = 0; k < 4; ++k) v[k] = (_Float16)hreg[j][k];
        *reinterpret_cast<f16x4*>(lds + r * 512 + ((lane * 8) ^ ((r & 7) << 4))) = v;
    }
    __syncthreads();

    f32x4 acc[2][2];

    for (int t = 0; t < T_STEPS; ++t) {
        const int cur = t & 1;
        char* Hc = lds + cur * 16384;
        char* Hn = lds + (cur ^ 1) * 16384;
        char* Sc = lds + 32768 + cur * 16384;
        char* Sn = lds + 32768 + (cur ^ 1) * 16384;
        const bool has_next = (t + 1 < T_STEPS);

        // 1. issue next-step H loads (latency hidden under this step's MFMAs)
        if (has_next) {
            const float* Ht1 = H + (size_t)(t + 1) * NROWS * DDIM;
#pragma unroll
            for (int j = 0; j < 4; ++j)
                hreg[j] = *reinterpret_cast<const f32x4*>(Ht1 + (size_t)srow[j] * DDIM + lane * 4);
        }

        // 2. init acc with bias (C/D: col = lane&15 -> bias indexed by et,lr)
#pragma unroll
        for (int nt = 0; nt < 2; ++nt)
#pragma unroll
            for (int et = 0; et < 2; ++et)
#pragma unroll
                for (int i = 0; i < 4; ++i) acc[nt][et][i] = bv[et];

        // 3. fused K-loop: acc += H_t@Wb^T  (+ S_{t-1}@Wa^T for t>0)
#pragma unroll
        for (int ks = 0; ks < 8; ++ks) {
            const int cbyte = ks * 64 + kg * 16;
            f16x8 hfrag[2], sfrag[2];
#pragma unroll
            for (int nt = 0; nt < 2; ++nt) {
                int r = nt * 16 + lr;
                int off = r * 512 + (cbyte ^ ((r & 7) << 4));
                hfrag[nt] = *reinterpret_cast<const f16x8*>(Hc + off);
                if (t > 0)
                    sfrag[nt] = *reinterpret_cast<const f16x8*>(Sc + off);
            }
#pragma unroll
            for (int et = 0; et < 2; ++et) {
                const int ct = wave * 2 + et;
                f16x8 wb = *reinterpret_cast<const f16x8*>(
                    WbF + (size_t)((ct * 8 + ks) * 64 + lane) * 8);
#pragma unroll
                for (int nt = 0; nt < 2; ++nt)
                    acc[nt][et] = __builtin_amdgcn_mfma_f32_16x16x32_f16(hfrag[nt], wb, acc[nt][et], 0, 0, 0);
                if (t > 0) {
                    f16x8 wa = *reinterpret_cast<const f16x8*>(
                        WaF + (size_t)((ct * 8 + ks) * 64 + lane) * 8);
#pragma unroll
                    for (int nt = 0; nt < 2; ++nt)
                        acc[nt][et] = __builtin_amdgcn_mfma_f32_16x16x32_f16(sfrag[nt], wa, acc[nt][et], 0, 0, 0);
                }
            }
        }

        // 4a. epilogue: cvt + write staged H_{t+1} into Hn
        if (has_next) {
#pragma unroll
            for (int j = 0; j < 4; ++j) {
                int r = wave * 4 + j;
                f16x4 v;
#pragma unroll
                for (int k = 0; k < 4; ++k) v[k] = (_Float16)hreg[j][k];
                *reinterpret_cast<f16x4*>(Hn + r * 512 + ((lane * 8) ^ ((r & 7) << 4))) = v;
            }
        }

        // 4b. epilogue: S_t -> Sn (f16) + d_out (f32)
        float* Ot = out + (size_t)t * NROWS * DDIM;
#pragma unroll
        for (int nt = 0; nt < 2; ++nt) {
#pragma unroll
            for (int et = 0; et < 2; ++et) {
                const int c = wave * 32 + et * 16 + lr;
#pragma unroll
                for (int i = 0; i < 4; ++i) {
                    int r = nt * 16 + kg * 4 + i;
                    float v = acc[nt][et][i];
                    *reinterpret_cast<_Float16*>(Sn + r * 512 + ((c * 2) ^ ((r & 7) << 4))) = (_Float16)v;
                    int gr = row0 + r;
                    if (gr < NROWS) Ot[(size_t)gr * DDIM + c] = v;
                }
            }
        }

        // 5. single barrier: Sn/Hn visible, and no wave can overwrite a buffer
        //    another wave still reads (writes go to the opposite buffer).
        __syncthreads();
    }
}

extern "C" void kernel_launch(void* const* d_in, const int* in_sizes, int n_in,
                              void* d_out, int out_size, void* d_ws, size_t ws_size,
                              hipStream_t stream)
{
    const float* H  = (const float*)d_in[0];
    const float* Aw = (const float*)d_in[1];
    const float* Bw = (const float*)d_in[2];
    const float* Bb = (const float*)d_in[3];
    float* out      = (float*)d_out;

    _Float16* wsA = (_Float16*)d_ws;         // 128 KiB
    _Float16* wsB = wsA + 65536;             // 128 KiB

    cvt_weights_kernel<<<32, 256, 0, stream>>>(Aw, Bw, wsA, wsB);

    int nblocks = (NROWS + ROWS_PB - 1) / ROWS_PB;   // 313
    ssm_fused_kernel<<<nblocks, 512, 0, stream>>>(H, wsA, wsB, Bb, out);
}

// Round 3
// 282.274 us; speedup vs baseline: 2.2703x; 2.2630x over previous
//
#include <hip/hip_runtime.h>
#include <hip/hip_fp16.h>

typedef _Float16 f16x8 __attribute__((ext_vector_type(8)));
typedef _Float16 f16x4 __attribute__((ext_vector_type(4)));
typedef float    f32x4 __attribute__((ext_vector_type(4)));

#define T_STEPS 32
#define NROWS   10000
#define DDIM    256
#define ROWS_PB 48
#define RPB_B   (ROWS_PB * 512)   // bytes per LDS tile (f16, 512B/row)

// ---------------------------------------------------------------------------
// Pre-kernel: f32 weights -> f16 MFMA B-fragments.
// Fragment (ct,ks), ct=0..15, ks=0..7:
//   dst[((ct*8+ks)*64+lane)*8 + j] = W[ct*16 + (lane&15)][ks*32 + (lane>>4)*8 + j]
// ---------------------------------------------------------------------------
__global__ __launch_bounds__(256) void cvt_weights_kernel(
    const float* __restrict__ Aw, const float* __restrict__ Bw,
    _Float16* __restrict__ wsA, _Float16* __restrict__ wsB)
{
    int tid  = blockIdx.x * 256 + threadIdx.x;      // 0..8191
    int lane = tid & 63;
    int ks   = (tid >> 6) & 7;
    int ct   = tid >> 9;                            // 0..15
    int e     = ct * 16 + (lane & 15);
    int dbase = ks * 32 + (lane >> 4) * 8;
    size_t src = (size_t)e * DDIM + dbase;
    size_t dst = (size_t)tid * 8;
#pragma unroll
    for (int j = 0; j < 8; ++j) {
        wsA[dst + j] = (_Float16)Aw[src + j];
        wsB[dst + j] = (_Float16)Bw[src + j];
    }
}

// ---------------------------------------------------------------------------
// Fused SSM. Block = 48 rows for all 32 steps. 8 waves; wave w owns cols
// [32w,32w+32). ALL weight fragments live in registers (128 VGPR/lane),
// loaded once -> K-loop touches only LDS + MFMA. Double-buffered LDS H tile
// (f16) + S exchange (f16), one barrier/step. Output stored via row-
// contiguous LDS readback: full 128B-line coalesced dwordx4 stores.
// ---------------------------------------------------------------------------
__global__ __launch_bounds__(512, 2) void ssm_fused_kernel(
    const float* __restrict__ H,          // [T][N][D] f32
    const _Float16* __restrict__ WaF,     // frag-permuted f16
    const _Float16* __restrict__ WbF,
    const float* __restrict__ bias,       // [D] f32
    float* __restrict__ out)              // [T][N][D] f32
{
    // Hbuf0 | Hbuf1 | Sbuf0 | Sbuf1, each 24 KiB
    __shared__ char lds[4 * RPB_B];

    const int tid  = threadIdx.x;
    const int lane = tid & 63;
    const int wave = tid >> 6;            // 0..7
    const int lr   = lane & 15;
    const int kg   = lane >> 4;           // 0..3
    const int row0 = blockIdx.x * ROWS_PB;

    // ---- one-time: weight fragments -> registers (32 x 1KiB wave loads) ----
    f16x8 wA[2][8], wB[2][8];
#pragma unroll
    for (int et = 0; et < 2; ++et) {
        const int ct = wave * 2 + et;
#pragma unroll
        for (int ks = 0; ks < 8; ++ks) {
            size_t o = (size_t)((ct * 8 + ks) * 64 + lane) * 8;
            wA[et][ks] = *reinterpret_cast<const f16x8*>(WaF + o);
            wB[et][ks] = *reinterpret_cast<const f16x8*>(WbF + o);
        }
    }

    // rows this wave stages into LDS (6 rows/wave, clamped for tail block)
    int srow[6];
#pragma unroll
    for (int j = 0; j < 6; ++j) {
        int r = row0 + wave * 6 + j;
        srow[j] = (r < NROWS) ? r : (NROWS - 1);
    }

    float bv[2];
#pragma unroll
    for (int et = 0; et < 2; ++et) bv[et] = bias[wave * 32 + et * 16 + lr];

    // ---- prologue: stage H_0 into Hbuf0 ----
    f32x4 hreg[6];
#pragma unroll
    for (int j = 0; j < 6; ++j)
        hreg[j] = *reinterpret_cast<const f32x4*>(H + (size_t)srow[j] * DDIM + lane * 4);
#pragma unroll
    for (int j = 0; j < 6; ++j) {
        int r = wave * 6 + j;
        f16x4 v;
#pragma unroll
        for (int k = 0; k < 4; ++k) v[k] = (_Float16)hreg[j][k];
        *reinterpret_cast<f16x4*>(lds + r * 512 + ((lane * 8) ^ ((r & 7) << 4))) = v;
    }
    __syncthreads();

    f32x4 acc[3][2];

    for (int t = 0; t < T_STEPS; ++t) {
        const int cur = t & 1;
        char* Hc = lds + cur * RPB_B;
        char* Hn = lds + (cur ^ 1) * RPB_B;
        char* Sc = lds + 2 * RPB_B + cur * RPB_B;
        char* Sn = lds + 2 * RPB_B + (cur ^ 1) * RPB_B;
        const bool has_next = (t + 1 < T_STEPS);

        // 1. issue next-step H loads (hidden under this step's K-loop)
        if (has_next) {
            const float* Ht1 = H + (size_t)(t + 1) * NROWS * DDIM;
#pragma unroll
            for (int j = 0; j < 6; ++j)
                hreg[j] = *reinterpret_cast<const f32x4*>(Ht1 + (size_t)srow[j] * DDIM + lane * 4);
        }

        // 2. init acc with bias (C/D: col = lane&15 -> bias per et,lr)
#pragma unroll
        for (int nt = 0; nt < 3; ++nt)
#pragma unroll
            for (int et = 0; et < 2; ++et)
#pragma unroll
                for (int i = 0; i < 4; ++i) acc[nt][et][i] = bv[et];

        // 3. K-loop: acc += H_t@Wb^T (+ S_{t-1}@Wa^T for t>0). LDS+MFMA only.
#pragma unroll
        for (int ks = 0; ks < 8; ++ks) {
            const int cbyte = ks * 64 + kg * 16;
            f16x8 hfrag[3], sfrag[3];
#pragma unroll
            for (int nt = 0; nt < 3; ++nt) {
                int r = nt * 16 + lr;
                int off = r * 512 + (cbyte ^ ((r & 7) << 4));
                hfrag[nt] = *reinterpret_cast<const f16x8*>(Hc + off);
                if (t > 0)
                    sfrag[nt] = *reinterpret_cast<const f16x8*>(Sc + off);
            }
#pragma unroll
            for (int et = 0; et < 2; ++et) {
#pragma unroll
                for (int nt = 0; nt < 3; ++nt)
                    acc[nt][et] = __builtin_amdgcn_mfma_f32_16x16x32_f16(hfrag[nt], wB[et][ks], acc[nt][et], 0, 0, 0);
                if (t > 0) {
#pragma unroll
                    for (int nt = 0; nt < 3; ++nt)
                        acc[nt][et] = __builtin_amdgcn_mfma_f32_16x16x32_f16(sfrag[nt], wA[et][ks], acc[nt][et], 0, 0, 0);
                }
            }
        }

        // 4a. stage H_{t+1} (f16) into Hn
        if (has_next) {
#pragma unroll
            for (int j = 0; j < 6; ++j) {
                int r = wave * 6 + j;
                f16x4 v;
#pragma unroll
                for (int k = 0; k < 4; ++k) v[k] = (_Float16)hreg[j][k];
                *reinterpret_cast<f16x4*>(Hn + r * 512 + ((lane * 8) ^ ((r & 7) << 4))) = v;
            }
        }

        // 4b. S_t -> Sn (f16, swizzled)
#pragma unroll
        for (int nt = 0; nt < 3; ++nt) {
#pragma unroll
            for (int et = 0; et < 2; ++et) {
                const int c = wave * 32 + et * 16 + lr;
#pragma unroll
                for (int i = 0; i < 4; ++i) {
                    int r = nt * 16 + kg * 4 + i;
                    *reinterpret_cast<_Float16*>(Sn + r * 512 + ((c * 2) ^ ((r & 7) << 4))) =
                        (_Float16)acc[nt][et][i];
                }
            }
        }

        // 5. barrier: Sn/Hn complete & visible
        __syncthreads();

        // 6. epilogue: row-contiguous readback of Sn -> coalesced f32 stores.
        //    Pass p: rows [16p,16p+16); thread covers 8 cols -> wave = 2 full
        //    1KiB rows; stores are full 128B lines.
        float* Ot = out + (size_t)t * NROWS * DDIM;
#pragma unroll
        for (int p = 0; p < 3; ++p) {
            int r  = p * 16 + (tid >> 5);          // 0..47
            int c8 = (tid & 31) * 8;               // 0..248
            f16x8 v = *reinterpret_cast<const f16x8*>(
                Sn + r * 512 + ((c8 * 2) ^ ((r & 7) << 4)));
            int gr = row0 + r;
            if (gr < NROWS) {
                f32x4 lo, hi;
#pragma unroll
                for (int k = 0; k < 4; ++k) { lo[k] = (float)v[k]; hi[k] = (float)v[k + 4]; }
                float* dst = Ot + (size_t)gr * DDIM + c8;
                *reinterpret_cast<f32x4*>(dst)     = lo;
                *reinterpret_cast<f32x4*>(dst + 4) = hi;
            }
        }
        // no barrier needed here: next step's writes target the opposite
        // buffers; all reads of this step's buffers are read-read with them.
    }
}

extern "C" void kernel_launch(void* const* d_in, const int* in_sizes, int n_in,
                              void* d_out, int out_size, void* d_ws, size_t ws_size,
                              hipStream_t stream)
{
    const float* H  = (const float*)d_in[0];
    const float* Aw = (const float*)d_in[1];
    const float* Bw = (const float*)d_in[2];
    const float* Bb = (const float*)d_in[3];
    float* out      = (float*)d_out;

    _Float16* wsA = (_Float16*)d_ws;         // 128 KiB
    _Float16* wsB = wsA + 65536;             // 128 KiB

    cvt_weights_kernel<<<32, 256, 0, stream>>>(Aw, Bw, wsA, wsB);

    int nblocks = (NROWS + ROWS_PB - 1) / ROWS_PB;   // 209 (< 256 CUs, 1 round)
    ssm_fused_kernel<<<nblocks, 512, 0, stream>>>(H, wsA, wsB, Bb, out);
}

// Round 4
// 238.643 us; speedup vs baseline: 2.6854x; 1.1828x over previous
//
#include <hip/hip_runtime.h>
#include <hip/hip_fp16.h>

typedef _Float16 f16x8 __attribute__((ext_vector_type(8)));
typedef _Float16 f16x4 __attribute__((ext_vector_type(4)));
typedef float    f32x4 __attribute__((ext_vector_type(4)));

#define T_STEPS 32
#define NROWS   10000
#define DDIM    256
#define ROWS_PB 48
#define RPB_B   (ROWS_PB * 512)   // bytes per LDS tile (f16, 512B/row)

// ---------------------------------------------------------------------------
// Pre-kernel: f32 weights -> f16 MFMA B-fragments.
// Fragment (ct,ks), ct=0..15, ks=0..7:
//   dst[((ct*8+ks)*64+lane)*8 + j] = W[ct*16 + (lane&15)][ks*32 + (lane>>4)*8 + j]
// ---------------------------------------------------------------------------
__global__ __launch_bounds__(256) void cvt_weights_kernel(
    const float* __restrict__ Aw, const float* __restrict__ Bw,
    _Float16* __restrict__ wsA, _Float16* __restrict__ wsB)
{
    int tid  = blockIdx.x * 256 + threadIdx.x;      // 0..8191
    int lane = tid & 63;
    int ks   = (tid >> 6) & 7;
    int ct   = tid >> 9;                            // 0..15
    int e     = ct * 16 + (lane & 15);
    int dbase = ks * 32 + (lane >> 4) * 8;
    size_t src = (size_t)e * DDIM + dbase;
    size_t dst = (size_t)tid * 8;
#pragma unroll
    for (int j = 0; j < 8; ++j) {
        wsA[dst + j] = (_Float16)Aw[src + j];
        wsB[dst + j] = (_Float16)Bw[src + j];
    }
}

// Barrier WITHOUT the compiler's vmcnt(0) drain: LDS deps are covered by
// lgkmcnt(0); global stores may keep draining across steps (never read back);
// global->reg prefetch is vmcnt-waited at its ds_write use by data dependency.
__device__ __forceinline__ void barrier_lgkm() {
    asm volatile("s_waitcnt lgkmcnt(0)\n\ts_barrier" ::: "memory");
}

// ---------------------------------------------------------------------------
// Fused SSM. Block = 48 rows x all 32 steps. 16 waves; wave w owns cols
// [16w,16w+16). Weights in registers (64 VGPR/lane). Double-buffered LDS
// H tile + S exchange, ONE lgkm-only barrier per step.
// ---------------------------------------------------------------------------
__global__ __launch_bounds__(1024, 4) void ssm_fused_kernel(
    const float* __restrict__ H,          // [T][N][D] f32
    const _Float16* __restrict__ WaF,     // frag-permuted f16
    const _Float16* __restrict__ WbF,
    const float* __restrict__ bias,       // [D] f32
    float* __restrict__ out)              // [T][N][D] f32
{
    // Hbuf0 | Hbuf1 | Sbuf0 | Sbuf1, each 24 KiB (96 KiB total)
    __shared__ char lds[4 * RPB_B];

    const int tid  = threadIdx.x;
    const int lane = tid & 63;
    const int wave = tid >> 6;            // 0..15 == ct (16-col tile)
    const int lr   = lane & 15;
    const int kg   = lane >> 4;           // 0..3
    const int row0 = blockIdx.x * ROWS_PB;

    // ---- one-time: this wave's weight fragments -> 64 VGPRs ----
    f16x8 wA[8], wB[8];
#pragma unroll
    for (int ks = 0; ks < 8; ++ks) {
        size_t o = (size_t)((wave * 8 + ks) * 64 + lane) * 8;
        wA[ks] = *reinterpret_cast<const f16x8*>(WaF + o);
        wB[ks] = *reinterpret_cast<const f16x8*>(WbF + o);
    }

    // rows this wave stages into LDS (3 rows/wave, clamped for tail block)
    int srow[3];
#pragma unroll
    for (int j = 0; j < 3; ++j) {
        int r = row0 + wave * 3 + j;
        srow[j] = (r < NROWS) ? r : (NROWS - 1);
    }

    const float bv = bias[wave * 16 + lr];

    // ---- prologue: stage H_0 (f32 -> f16, swizzled) into Hbuf0 ----
    f32x4 hreg[3];
#pragma unroll
    for (int j = 0; j < 3; ++j)
        hreg[j] = *reinterpret_cast<const f32x4*>(H + (size_t)srow[j] * DDIM + lane * 4);
#pragma unroll
    for (int j = 0; j < 3; ++j) {
        int r = wave * 3 + j;
        f16x4 v;
#pragma unroll
        for (int k = 0; k < 4; ++k) v[k] = (_Float16)hreg[j][k];
        *reinterpret_cast<f16x4*>(lds + r * 512 + ((lane * 8) ^ ((r & 7) << 4))) = v;
    }
    __syncthreads();

    f32x4 acc[3];

    for (int t = 0; t < T_STEPS; ++t) {
        const int cur = t & 1;
        char* Hc = lds + cur * RPB_B;
        char* Hn = lds + (cur ^ 1) * RPB_B;
        char* Sc = lds + 2 * RPB_B + cur * RPB_B;
        char* Sn = lds + 2 * RPB_B + (cur ^ 1) * RPB_B;
        const bool has_next = (t + 1 < T_STEPS);

        // 1. issue next-step H loads (hidden under this step's K-loop)
        if (has_next) {
            const float* Ht1 = H + (size_t)(t + 1) * NROWS * DDIM;
#pragma unroll
            for (int j = 0; j < 3; ++j)
                hreg[j] = *reinterpret_cast<const f32x4*>(Ht1 + (size_t)srow[j] * DDIM + lane * 4);
        }

        // 2. init acc with bias (C/D: col = lane&15)
#pragma unroll
        for (int nt = 0; nt < 3; ++nt)
#pragma unroll
            for (int i = 0; i < 4; ++i) acc[nt][i] = bv;

        // 3. K-loop: acc += H_t@Wb^T (+ S_{t-1}@Wa^T for t>0). LDS+MFMA only.
#pragma unroll
        for (int ks = 0; ks < 8; ++ks) {
            const int cbyte = ks * 64 + kg * 16;
            f16x8 hfrag[3];
#pragma unroll
            for (int nt = 0; nt < 3; ++nt) {
                int r = nt * 16 + lr;
                hfrag[nt] = *reinterpret_cast<const f16x8*>(
                    Hc + r * 512 + (cbyte ^ ((r & 7) << 4)));
            }
#pragma unroll
            for (int nt = 0; nt < 3; ++nt)
                acc[nt] = __builtin_amdgcn_mfma_f32_16x16x32_f16(hfrag[nt], wB[ks], acc[nt], 0, 0, 0);
            if (t > 0) {
                f16x8 sfrag[3];
#pragma unroll
                for (int nt = 0; nt < 3; ++nt) {
                    int r = nt * 16 + lr;
                    sfrag[nt] = *reinterpret_cast<const f16x8*>(
                        Sc + r * 512 + (cbyte ^ ((r & 7) << 4)));
                }
#pragma unroll
                for (int nt = 0; nt < 3; ++nt)
                    acc[nt] = __builtin_amdgcn_mfma_f32_16x16x32_f16(sfrag[nt], wA[ks], acc[nt], 0, 0, 0);
            }
        }

        // 4a. stage H_{t+1} (f16) into Hn (vmcnt waits happen here by dep)
        if (has_next) {
#pragma unroll
            for (int j = 0; j < 3; ++j) {
                int r = wave * 3 + j;
                f16x4 v;
#pragma unroll
                for (int k = 0; k < 4; ++k) v[k] = (_Float16)hreg[j][k];
                *reinterpret_cast<f16x4*>(Hn + r * 512 + ((lane * 8) ^ ((r & 7) << 4))) = v;
            }
        }

        // 4b. S_t -> Sn (f16, swizzled)
#pragma unroll
        for (int nt = 0; nt < 3; ++nt) {
            const int c = wave * 16 + lr;
#pragma unroll
            for (int i = 0; i < 4; ++i) {
                int r = nt * 16 + kg * 4 + i;
                *reinterpret_cast<_Float16*>(Sn + r * 512 + ((c * 2) ^ ((r & 7) << 4))) =
                    (_Float16)acc[nt][i];
            }
        }

        // 5. single lgkm-only barrier: Sn/Hn complete & visible; output
        //    stores keep draining in the background.
        barrier_lgkm();

        // 6. epilogue: row-contiguous readback of Sn -> coalesced f32 stores.
        //    1536 chunks of 16B (48 rows x 32); threads 0..1023 + 0..511.
        float* Ot = out + (size_t)t * NROWS * DDIM;
#pragma unroll
        for (int p = 0; p < 2; ++p) {
            int idx = p * 1024 + tid;
            if (idx < ROWS_PB * 32) {
                int r   = idx >> 5;                // 0..47
                int c16 = idx & 31;                // 16B chunk within row
                f16x8 v = *reinterpret_cast<const f16x8*>(
                    Sn + r * 512 + ((c16 * 16) ^ ((r & 7) << 4)));
                int gr = row0 + r;
                if (gr < NROWS) {
                    f32x4 lo, hi;
#pragma unroll
                    for (int k = 0; k < 4; ++k) { lo[k] = (float)v[k]; hi[k] = (float)v[k + 4]; }
                    float* dst = Ot + (size_t)gr * DDIM + c16 * 8;
                    *reinterpret_cast<f32x4*>(dst)     = lo;
                    *reinterpret_cast<f32x4*>(dst + 4) = hi;
                }
            }
        }
        // no second barrier: next step's LDS writes target the opposite
        // buffers; this epilogue's reads complete before this wave's next
        // lgkmcnt(0)+barrier, which precedes any conflicting write (t+2).
    }
}

extern "C" void kernel_launch(void* const* d_in, const int* in_sizes, int n_in,
                              void* d_out, int out_size, void* d_ws, size_t ws_size,
                              hipStream_t stream)
{
    const float* H  = (const float*)d_in[0];
    const float* Aw = (const float*)d_in[1];
    const float* Bw = (const float*)d_in[2];
    const float* Bb = (const float*)d_in[3];
    float* out      = (float*)d_out;

    _Float16* wsA = (_Float16*)d_ws;         // 128 KiB
    _Float16* wsB = wsA + 65536;             // 128 KiB

    cvt_weights_kernel<<<32, 256, 0, stream>>>(Aw, Bw, wsA, wsB);

    int nblocks = (NROWS + ROWS_PB - 1) / ROWS_PB;   // 209 (< 256 CUs, 1 round)
    ssm_fused_kernel<<<nblocks, 1024, 0, stream>>>(H, wsA, wsB, Bb, out);
}